// Round 14
// baseline (167.544 us; speedup 1.0000x reference)
//
#include <hip/hip_runtime.h>
#include <math.h>

#define NB 4
#define NN 512

// ---------------- kA: ha = X@Wa + b1, hb = X@Wb ; zero ru ----------------
__global__ void kA(const float* __restrict__ X, const float* __restrict__ W1,
                   const float* __restrict__ b1, float* __restrict__ ha,
                   float* __restrict__ hb, float* __restrict__ ru) {
  int b = blockIdx.y, n0 = blockIdx.x * 8;
  __shared__ float xs[8][128];
  int t = threadIdx.x;  // 128 threads
  for (int q = t; q < 1024; q += 128) {
    int r = q >> 7, f = q & 127;
    xs[r][f] = X[(size_t)(b * NN + n0 + r) * 128 + f];
  }
  int flat = b * 64 + blockIdx.x;
  if (flat < 16) ru[flat * 128 + t] = 0.f;
  __syncthreads();
  float accA[8] = {0,0,0,0,0,0,0,0}, accB[8] = {0,0,0,0,0,0,0,0};
  for (int f = 0; f < 128; ++f) {
    float wa = W1[f * 128 + t];
    float wb = W1[(128 + f) * 128 + t];
#pragma unroll
    for (int r = 0; r < 8; ++r) {
      accA[r] = fmaf(xs[r][f], wa, accA[r]);
      accB[r] = fmaf(xs[r][f], wb, accB[r]);
    }
  }
  float b1v = b1[t];
#pragma unroll
  for (int r = 0; r < 8; ++r) {
    ha[(size_t)(b * NN + n0 + r) * 128 + t] = accA[r] + b1v;
    hb[(size_t)(b * NN + n0 + r) * 128 + t] = accB[r];
  }
}

// ===== device roles =====================================================

// kB as a device role (256 thr): K tile + row-sum atomics.
// sm layout (floats): As 0..4224, Bs 4224..8448, wd 8448..8576,
//                     w2 8576..8704, ci 8704..8800, cj 8800..8896
__device__ __forceinline__ void dKb(const float* __restrict__ ha,
                                    const float* __restrict__ hb,
                                    const float* __restrict__ coords,
                                    const float* __restrict__ W1,
                                    const float* __restrict__ W2,
                                    const float* __restrict__ b2,
                                    float* __restrict__ Km,
                                    float* __restrict__ ru,
                                    float* sm, int jc, int ic, int b) {
  float* As = sm;
  float* Bs = sm + 4224;
  float* wd = sm + 8448;
  float* w2 = sm + 8576;
  float* ci = sm + 8704;
  float* cj = sm + 8800;
  int i0 = ic * 32, j0 = jc * 32;
  int t = threadIdx.x;  // 256
  for (int q = t; q < 1024; q += 256) {
    int r = q >> 5, c = (q & 31) * 4;
    *(float4*)&As[r * 132 + c] = *(const float4*)&ha[(size_t)(b * NN + i0 + r) * 128 + c];
    *(float4*)&Bs[r * 132 + c] = *(const float4*)&hb[(size_t)(b * NN + j0 + r) * 128 + c];
  }
  if (t < 128) { wd[t] = W1[256 * 128 + t]; w2[t] = W2[t]; }
  if (t < 96) ci[t] = coords[(size_t)(b * NN + i0) * 3 + t];
  else if (t < 192) cj[t - 96] = coords[(size_t)(b * NN + j0) * 3 + (t - 96)];
  __syncthreads();
  int tx = t & 15, ty = t >> 4;
  int ia = 2 * ty, ib = ia + 1, ja = tx, jb = tx + 16;
  float d00, d01, d10, d11;
  {
    float ax = ci[ia * 3], ay = ci[ia * 3 + 1], az = ci[ia * 3 + 2];
    float bx = ci[ib * 3], by = ci[ib * 3 + 1], bz = ci[ib * 3 + 2];
    float cx0 = cj[ja * 3], cy0 = cj[ja * 3 + 1], cz0 = cj[ja * 3 + 2];
    float cx1 = cj[jb * 3], cy1 = cj[jb * 3 + 1], cz1 = cj[jb * 3 + 2];
    float dx, dy, dz;
    dx = ax - cx0; dy = ay - cy0; dz = az - cz0;
    d00 = sqrtf(fmaxf(dx * dx + dy * dy + dz * dz, 0.f));
    dx = ax - cx1; dy = ay - cy1; dz = az - cz1;
    d01 = sqrtf(fmaxf(dx * dx + dy * dy + dz * dz, 0.f));
    dx = bx - cx0; dy = by - cy0; dz = bz - cz0;
    d10 = sqrtf(fmaxf(dx * dx + dy * dy + dz * dz, 0.f));
    dx = bx - cx1; dy = by - cy1; dz = bz - cz1;
    d11 = sqrtf(fmaxf(dx * dx + dy * dy + dz * dz, 0.f));
  }
  float a00 = 0, a01 = 0, a10 = 0, a11 = 0;
  for (int k = 0; k < 128; k += 4) {
    float4 A0 = *(float4*)&As[ia * 132 + k];
    float4 A1 = *(float4*)&As[ib * 132 + k];
    float4 B0 = *(float4*)&Bs[ja * 132 + k];
    float4 B1 = *(float4*)&Bs[jb * 132 + k];
    float4 W = *(float4*)&wd[k];
    float4 V = *(float4*)&w2[k];
#pragma unroll
    for (int kk = 0; kk < 4; ++kk) {
      float av = ((float*)&A0)[kk], av1 = ((float*)&A1)[kk];
      float bv = ((float*)&B0)[kk], bv1 = ((float*)&B1)[kk];
      float wv = ((float*)&W)[kk], vv = ((float*)&V)[kk];
      float t00 = fmaxf(fmaf(d00, wv, av + bv), 0.f);
      float t01 = fmaxf(fmaf(d01, wv, av + bv1), 0.f);
      float t10 = fmaxf(fmaf(d10, wv, av1 + bv), 0.f);
      float t11 = fmaxf(fmaf(d11, wv, av1 + bv1), 0.f);
      a00 = fmaf(t00, vv, a00);
      a01 = fmaf(t01, vv, a01);
      a10 = fmaf(t10, vv, a10);
      a11 = fmaf(t11, vv, a11);
    }
  }
  float b2v = b2[0];
  float k00 = __expf(-5.0f * (a00 + b2v));
  float k01 = __expf(-5.0f * (a01 + b2v));
  float k10 = __expf(-5.0f * (a10 + b2v));
  float k11 = __expf(-5.0f * (a11 + b2v));
  size_t r0 = (size_t)(b * NN + i0 + ia) * NN + j0;
  size_t r1 = (size_t)(b * NN + i0 + ib) * NN + j0;
  Km[r0 + ja] = k00; Km[r0 + jb] = k01;
  Km[r1 + ja] = k10; Km[r1 + jb] = k11;
  float s0 = k00 + k01, s1 = k10 + k11;
#pragma unroll
  for (int off = 1; off < 16; off <<= 1) {
    s0 += __shfl_xor(s0, off);
    s1 += __shfl_xor(s1, off);
  }
  if (tx == 0) {
    atomicAdd(&ru[b * NN + i0 + ia], s0);
    atomicAdd(&ru[b * NN + i0 + ib], s1);
  }
}

// GAT GEMM + logit projections, 256 thr (proven round-5 kG1f body).
// sm: xs 0..1024, red 1024..1152 ([4 waves][8 r][4])
__device__ __forceinline__ void dG1f256(const float* __restrict__ x,
                                        const float* __restrict__ Wg,
                                        const float* __restrict__ asrc,
                                        const float* __restrict__ adst,
                                        float* __restrict__ xw,
                                        float* __restrict__ ssT,
                                        float* __restrict__ sdT,
                                        float* sm, int bx, int b) {
  int n0 = bx * 8;
  float* xs = sm;           // [8][128]
  float* red = sm + 1024;   // [4][8][4]
  int t = threadIdx.x;  // 256
  for (int q = t; q < 1024; q += 256)
    xs[q] = x[(size_t)(b * NN + n0 + (q >> 7)) * 128 + (q & 127)];
  __syncthreads();
  int c0 = t, c1 = t + 256;
  float acc0[8] = {0,0,0,0,0,0,0,0}, acc1[8] = {0,0,0,0,0,0,0,0};
  for (int f = 0; f < 128; ++f) {
    float w0 = Wg[f * 512 + c0], w1 = Wg[f * 512 + c1];
#pragma unroll
    for (int r = 0; r < 8; ++r) {
      float xv = xs[r * 128 + f];
      acc0[r] = fmaf(xv, w0, acc0[r]);
      acc1[r] = fmaf(xv, w1, acc1[r]);
    }
  }
#pragma unroll
  for (int r = 0; r < 8; ++r) {
    xw[(size_t)(b * NN + n0 + r) * 512 + c0] = acc0[r];
    xw[(size_t)(b * NN + n0 + r) * 512 + c1] = acc1[r];
  }
  float as0 = asrc[c0], ad0 = adst[c0];
  float as1 = asrc[c1], ad1 = adst[c1];
  int w = t >> 6, l = t & 63;
#pragma unroll
  for (int r = 0; r < 8; ++r) {
    float ps0 = acc0[r] * as0, pd0 = acc0[r] * ad0;
    float ps1 = acc1[r] * as1, pd1 = acc1[r] * ad1;
#pragma unroll
    for (int off = 1; off < 64; off <<= 1) {
      ps0 += __shfl_xor(ps0, off);
      pd0 += __shfl_xor(pd0, off);
      ps1 += __shfl_xor(ps1, off);
      pd1 += __shfl_xor(pd1, off);
    }
    if (l == 0) {
      red[w * 32 + r * 4 + 0] = ps0; red[w * 32 + r * 4 + 1] = pd0;
      red[w * 32 + r * 4 + 2] = ps1; red[w * 32 + r * 4 + 3] = pd1;
    }
  }
  __syncthreads();
  if (t < 64) {
    int r = t & 7, h = (t >> 3) & 3, sd = t >> 5;
    int wbase = (h & 1) ? 2 : 0;
    int which = (h < 2 ? 0 : 2) + sd;
    float s = red[wbase * 32 + r * 4 + which] + red[(wbase + 1) * 32 + r * 4 + which];
    float* dst = sd ? sdT : ssT;
    dst[(size_t)(b * 4 + h) * 512 + n0 + r] = s;
  }
}

// Sinkhorn first col-partials: rvp[ic] = partial col sums of K * (1/ru)
__device__ __forceinline__ void dCcol(const float* __restrict__ Km,
                                      const float* __restrict__ ru,
                                      float* __restrict__ rvp,
                                      float* sm, int ic, int b) {
  float* uinv = sm;  // 32
  int t = threadIdx.x;
  if (t < 32) uinv[t] = 1.0f / ru[b * NN + ic * 32 + t];
  __syncthreads();
  const float* Kp = Km + (size_t)(b * NN + ic * 32) * NN + t;
  float acc = 0.f;
#pragma unroll 8
  for (int ii = 0; ii < 32; ++ii) acc = fmaf(Kp[(size_t)ii * NN], uinv[ii], acc);
  rvp[ic * 2048 + b * NN + t] = acc;
}

// Sinkhorn iteration: row pass + new col partials
__device__ __forceinline__ void dCrc(const float* __restrict__ Km,
                                     const float* __restrict__ rvpOld,
                                     float* __restrict__ rvpNew,
                                     float* __restrict__ ru,
                                     float* sm, int ic, int b) {
  float* vinv = sm;        // 512
  float* uinv = sm + 512;  // 32
  int t = threadIdx.x;
  {
    float s = 0.f;
#pragma unroll
    for (int q = 0; q < 16; ++q) s += rvpOld[q * 2048 + b * NN + t];
    vinv[t] = 1.0f / s;
  }
  __syncthreads();
  int w = t >> 6, l = t & 63;
#pragma unroll
  for (int m = 0; m < 4; ++m) {
    int r = ic * 32 + w * 4 + m;
    const float* Kp = Km + (size_t)(b * NN + r) * NN;
    float acc = 0.f;
#pragma unroll
    for (int mm = 0; mm < 8; ++mm) acc = fmaf(Kp[l + 64 * mm], vinv[l + 64 * mm], acc);
#pragma unroll
    for (int off = 1; off < 64; off <<= 1) acc += __shfl_xor(acc, off);
    if (l == 0) { uinv[w * 4 + m] = 1.0f / acc; ru[b * NN + r] = acc; }
  }
  __syncthreads();
  {
    const float* Kp = Km + (size_t)(b * NN + ic * 32) * NN + t;
    float acc = 0.f;
#pragma unroll 8
    for (int ii = 0; ii < 32; ++ii) acc = fmaf(Kp[(size_t)ii * NN], uinv[ii], acc);
    rvpNew[ic * 2048 + b * NN + t] = acc;
  }
}

// GAT GEMM + logit projections, 512 thr (layer-1 rider)
__device__ __forceinline__ void dG1f(const float* __restrict__ x,
                                     const float* __restrict__ Wg,
                                     const float* __restrict__ asrc,
                                     const float* __restrict__ adst,
                                     float* __restrict__ xw,
                                     float* __restrict__ ssT,
                                     float* __restrict__ sdT,
                                     float* sm, int bx, int b) {
  int n0 = bx * 8;
  float* xs = sm;          // 1024: [8][128]
  float* red = sm + 1024;  // 128: [8 waves][8 r][2]
  int t = threadIdx.x;  // 512
  for (int q = t; q < 1024; q += 512)
    xs[q] = x[(size_t)(b * NN + n0 + (q >> 7)) * 128 + (q & 127)];
  __syncthreads();
  int c = t;
  float acc[8] = {0,0,0,0,0,0,0,0};
  for (int f = 0; f < 128; ++f) {
    float w0 = Wg[f * 512 + c];
#pragma unroll
    for (int r = 0; r < 8; ++r) acc[r] = fmaf(xs[r * 128 + f], w0, acc[r]);
  }
#pragma unroll
  for (int r = 0; r < 8; ++r)
    xw[(size_t)(b * NN + n0 + r) * 512 + c] = acc[r];
  float asv = asrc[c], adv = adst[c];
  int w = t >> 6, l = t & 63;
#pragma unroll
  for (int r = 0; r < 8; ++r) {
    float ps = acc[r] * asv, pd = acc[r] * adv;
#pragma unroll
    for (int off = 1; off < 64; off <<= 1) {
      ps += __shfl_xor(ps, off);
      pd += __shfl_xor(pd, off);
    }
    if (l == 0) { red[w * 16 + r * 2] = ps; red[w * 16 + r * 2 + 1] = pd; }
  }
  __syncthreads();
  if (t < 64) {
    int h = t >> 4, rr = t & 7, sd = (t >> 3) & 1;
    float s = red[(2 * h) * 16 + rr * 2 + sd] + red[(2 * h + 1) * 16 + rr * 2 + sd];
    float* dst = sd ? sdT : ssT;
    dst[(size_t)(b * 4 + h) * 512 + n0 + rr] = s;
  }
}

// GAT softmax+PV, ONE head, 8-row i-tile, j-SPLIT x2 (s = slice).
// partial[s*1048576 + ((b*4+h)*512 + i)*128 + f] = PV over j in slice s.
#define PLT 520
__device__ __forceinline__ void dG2tj(const float* __restrict__ xw,
                                      const float* __restrict__ ssT,
                                      const float* __restrict__ sdT,
                                      float* __restrict__ partial,
                                      float* sm, int bx, int b) {
  int s = bx & 1, h = (bx >> 1) & 3, i0 = (bx >> 3) * 8;
  int bh = b * 4 + h;
  float* pls = sm;             // [8][520]; sc4 reuses sm
  float* ssb = sm + 8192;      // 512
  float* sdl = sm + 8704;      // 8
  float* smaxsh = sm + 8712;   // 8
  float* mxl = sm + 8720;      // 8
  int t = threadIdx.x;  // 512
  {
    float v = ssT[(size_t)bh * 512 + t];
    ssb[t] = v;
#pragma unroll
    for (int off = 1; off < 64; off <<= 1) v = fmaxf(v, __shfl_xor(v, off));
    if ((t & 63) == 0) smaxsh[t >> 6] = v;
  }
  if (t < 8) sdl[t] = sdT[(size_t)bh * 512 + i0 + t];
  __syncthreads();
  if (t < 8) {
    float m = smaxsh[0];
#pragma unroll
    for (int q = 1; q < 8; ++q) m = fmaxf(m, smaxsh[q]);
    float mm = sdl[t] + m;
    mxl[t] = (mm >= 0.f) ? mm : 0.2f * mm;
  }
  __syncthreads();
  // phase A: full 512-j P build (denominator is global over j)
  {
    int il = t >> 6, jq = t & 63;
    float mx = mxl[il], sdv = sdl[il];
    float pe[8];
    float den = 0.f;
#pragma unroll
    for (int jj = 0; jj < 8; ++jj) {
      int j = jj * 64 + jq;
      float e = sdv + ssb[j];
      e = (e >= 0.f) ? e : 0.2f * e;
      pe[jj] = __expf(e - mx);
      den += pe[jj];
    }
#pragma unroll
    for (int off = 1; off < 64; off <<= 1) den += __shfl_xor(den, off);
    float inv = 1.0f / (4.0f * den);
#pragma unroll
    for (int jj = 0; jj < 8; ++jj) pls[il * PLT + jj * 64 + jq] = pe[jj] * inv;
  }
  __syncthreads();
  // phase B: this block covers only j in [s*256, s*256+256)
  int fq = t & 31, jh = t >> 5;
  const float* xp = xw + (size_t)(b * NN) * 512 + h * 128 + fq * 4;
  float4 acc[8];
#pragma unroll
  for (int r = 0; r < 8; ++r) acc[r] = make_float4(0.f, 0.f, 0.f, 0.f);
  int jbase = s * 256 + jh * 16;
#pragma unroll 4
  for (int jj = 0; jj < 16; ++jj) {
    int j = jbase + jj;
    float4 xv = *(const float4*)&xp[(size_t)j * 512];
#pragma unroll
    for (int r = 0; r < 8; ++r) {
      float p = pls[r * PLT + j];   // same-address broadcast per half-wave
      acc[r].x = fmaf(p, xv.x, acc[r].x);
      acc[r].y = fmaf(p, xv.y, acc[r].y);
      acc[r].z = fmaf(p, xv.z, acc[r].z);
      acc[r].w = fmaf(p, xv.w, acc[r].w);
    }
  }
  __syncthreads();  // all pls reads done before sc4 overwrite
  int w = t >> 6;
#pragma unroll
  for (int r = 0; r < 8; ++r) {
    acc[r].x += __shfl_xor(acc[r].x, 32);
    acc[r].y += __shfl_xor(acc[r].y, 32);
    acc[r].z += __shfl_xor(acc[r].z, 32);
    acc[r].w += __shfl_xor(acc[r].w, 32);
  }
  float4* sc4 = (float4*)sm;
  if ((t & 63) < 32) {
#pragma unroll
    for (int r = 0; r < 8; ++r) sc4[w * 256 + r * 32 + fq] = acc[r];
  }
  __syncthreads();
  if (t < 256) {
    int r = t >> 5, ff = t & 31;
    float4 o = make_float4(0.f, 0.f, 0.f, 0.f);
#pragma unroll
    for (int q = 0; q < 8; ++q) {
      float4 u = sc4[q * 256 + r * 32 + ff];
      o.x += u.x; o.y += u.y; o.z += u.z; o.w += u.w;
    }
    *(float4*)&partial[(size_t)s * 1048576 +
                       ((size_t)bh * NN + i0 + r) * 128 + ff * 4] = o;
  }
}

// head+slice reduce: xo[b,i,f] = sum_{h,s} partial[s][b,h,i,f] + bg[f]
__device__ __forceinline__ void dRed8(const float* __restrict__ partial,
                                      const float* __restrict__ bg,
                                      float* __restrict__ xo, int bx, int b) {
  int idx = bx * 512 + threadIdx.x;  // 0..16383 per b: i*32 + f4
  int f4 = idx & 31, i = idx >> 5;
  const float* pp = partial + (((size_t)b * 4) * NN + i) * 128 + f4 * 4;
  float4 bb = *(const float4*)&bg[f4 * 4];
  float4 s = bb;
#pragma unroll
  for (int sl = 0; sl < 2; ++sl) {
#pragma unroll
    for (int h = 0; h < 4; ++h) {
      float4 v = *(const float4*)&pp[(size_t)sl * 1048576 + (size_t)h * NN * 128];
      s.x += v.x; s.y += v.y; s.z += v.z; s.w += v.w;
    }
  }
  *(float4*)&xo[(size_t)(b * NN + i) * 128 + f4 * 4] = s;
}

// final_adj tile, 512 thr: 32x32, 2 outputs/thread
__device__ __forceinline__ void dF(const float* __restrict__ x,
                                   float* __restrict__ out,
                                   float* sm, int fid, int b) {
  int i0 = (fid >> 4) * 32, j0 = (fid & 15) * 32;
  float* As = sm;          // [32][132]
  float* Bs = sm + 4224;   // [32][132]
  int t = threadIdx.x;  // 512
  for (int q = t; q < 1024; q += 512) {
    int r = q >> 5, c = (q & 31) * 4;
    *(float4*)&As[r * 132 + c] = *(const float4*)&x[(size_t)(b * NN + i0 + r) * 128 + c];
    *(float4*)&Bs[r * 132 + c] = *(const float4*)&x[(size_t)(b * NN + j0 + r) * 128 + c];
  }
  __syncthreads();
  int tx = t & 31, ty = t >> 5;
  int ia = 2 * ty, ib = ia + 1;
  float a0 = 0.f, a1 = 0.f;
  for (int k = 0; k < 128; k += 4) {
    float4 A0 = *(float4*)&As[ia * 132 + k];
    float4 A1 = *(float4*)&As[ib * 132 + k];
    float4 B0 = *(float4*)&Bs[tx * 132 + k];
#pragma unroll
    for (int kk = 0; kk < 4; ++kk) {
      a0 = fmaf(((float*)&A0)[kk], ((float*)&B0)[kk], a0);
      a1 = fmaf(((float*)&A1)[kk], ((float*)&B0)[kk], a1);
    }
  }
  out[(size_t)(b * NN + i0 + ia) * NN + j0 + tx] = 1.0f / (1.0f + __expf(-a0));
  out[(size_t)(b * NN + i0 + ib) * NN + j0 + tx] = 1.0f / (1.0f + __expf(-a1));
}

// ================= combined node kernels ================================

// kB tiles (bx < 256) + G1f(L0) riders (bx in [256, 320)), 256 thr
__global__ __launch_bounds__(256) void nKbG1f(
    const float* ha, const float* hb, const float* C, const float* W1,
    const float* W2, const float* b2, float* Km, float* ru,
    const float* X, const float* Wg, const float* as_, const float* ad_,
    float* xw, float* ssT, float* sdT) {
  __shared__ alignas(16) float sm[8896];
  if (blockIdx.x < 256)
    dKb(ha, hb, C, W1, W2, b2, Km, ru, sm, blockIdx.x & 15, blockIdx.x >> 4,
        blockIdx.y);
  else
    dG1f256(X, Wg, as_, ad_, xw, ssT, sdT, sm, blockIdx.x - 256, blockIdx.y);
}

__global__ __launch_bounds__(512) void kCcol(
    const float* Km, const float* ru, float* rvp) {
  __shared__ float sm[32];
  dCcol(Km, ru, rvp, sm, blockIdx.x, blockIdx.y);
}

__global__ __launch_bounds__(512) void nCrcG2t(
    const float* Km, const float* rvpOld, float* rvpNew, float* ru,
    const float* xw, const float* ssT, const float* sdT, float* partial) {
  __shared__ alignas(16) float sm[8728];
  if (blockIdx.x < 16) dCrc(Km, rvpOld, rvpNew, ru, sm, blockIdx.x, blockIdx.y);
  else dG2tj(xw, ssT, sdT, partial, sm, blockIdx.x - 16, blockIdx.y);
}

__global__ __launch_bounds__(512) void nCrcRed(
    const float* Km, const float* rvpOld, float* rvpNew, float* ru,
    const float* partial, const float* bg, float* xo) {
  __shared__ alignas(16) float sm[544];
  if (blockIdx.x < 16) dCrc(Km, rvpOld, rvpNew, ru, sm, blockIdx.x, blockIdx.y);
  else dRed8(partial, bg, xo, blockIdx.x - 16, blockIdx.y);
}

__global__ __launch_bounds__(512) void nCrcG1f(
    const float* Km, const float* rvpOld, float* rvpNew, float* ru,
    const float* x, const float* Wg, const float* as_, const float* ad_,
    float* xw, float* ssT, float* sdT) {
  __shared__ alignas(16) float sm[1280];
  if (blockIdx.x < 16) dCrc(Km, rvpOld, rvpNew, ru, sm, blockIdx.x, blockIdx.y);
  else dG1f(x, Wg, as_, ad_, xw, ssT, sdT, sm, blockIdx.x - 16, blockIdx.y);
}

// crc + 64-tile slice of final_adj (kF spread across the trailing chain)
__global__ __launch_bounds__(512) void nCrcFp(
    const float* Km, const float* rvpOld, float* rvpNew, float* ru,
    const float* x, float* outF, int fbase) {
  __shared__ alignas(16) float sm[8448];
  if (blockIdx.x < 16) dCrc(Km, rvpOld, rvpNew, ru, sm, blockIdx.x, blockIdx.y);
  else dF(x, outF, sm, fbase + (blockIdx.x - 16), blockIdx.y);
}

// ------- kAdj: adj = (1/ru_i) * K * (1/rv_j) -----------------------------
__global__ __launch_bounds__(512) void kAdj(const float* __restrict__ Km,
                                            const float* __restrict__ ru,
                                            const float* __restrict__ rvp,
                                            float* __restrict__ out) {
  int rc = blockIdx.x, b = blockIdx.y;  // (16, 4)
  __shared__ float vinv[512];
  __shared__ float uinv[32];
  int t = threadIdx.x;  // 512
  {
    float s = 0.f;
#pragma unroll
    for (int ic = 0; ic < 16; ++ic) s += rvp[ic * 2048 + b * NN + t];
    vinv[t] = 1.0f / s;
  }
  if (t < 32) uinv[t] = 1.0f / ru[b * NN + rc * 32 + t];
  __syncthreads();
  float vj = vinv[t];
  const float* Kp = Km + (size_t)(b * NN + rc * 32) * NN + t;
  float* op = out + (size_t)(b * NN + rc * 32) * NN + t;
#pragma unroll 4
  for (int m = 0; m < 32; ++m) {
    op[(size_t)m * NN] = Kp[(size_t)m * NN] * uinv[m] * vj;
  }
}

extern "C" void kernel_launch(void* const* d_in, const int* in_sizes, int n_in,
                              void* d_out, int out_size, void* d_ws, size_t ws_size,
                              hipStream_t stream) {
  (void)in_sizes; (void)n_in; (void)out_size; (void)ws_size;
  const float* X   = (const float*)d_in[0];
  const float* C   = (const float*)d_in[1];
  const float* W1  = (const float*)d_in[2];
  const float* b1  = (const float*)d_in[3];
  const float* W2  = (const float*)d_in[4];
  const float* b2  = (const float*)d_in[5];
  const float* Wg  = (const float*)d_in[6];
  const float* as_ = (const float*)d_in[7];
  const float* ad_ = (const float*)d_in[8];
  const float* bg  = (const float*)d_in[9];
  float* out = (float*)d_out;
  float* ws = (float*)d_ws;

  float* ha    = ws;                 // 262144
  float* hb    = ws + 262144;        // 262144
  float* Km    = ws + 524288;        // 1048576
  float* ru    = ws + 1572864;       // 2048
  float* xw    = ws + 1591296;       // 1048576
  float* ssT   = ws + 2639872;       // 8192
  float* sdT   = ws + 2648064;       // 8192
  float* x1    = ws + 2656256;       // 262144
  float* x2    = ws + 2918400;       // 262144
  float* rvpA  = ws + 3180544;       // 32768
  float* rvpB  = ws + 3246080;       // 32768
  float* adj   = out + 1048576;
  // partial (2 slices x 1048576) aliases the WHOLE out buffer: final_adj
  // region is written only by nCrcFp (it5..it8) and adj only by kAdj (last);
  // both partial slices are dead after each layer's Red node.
  float* partial = out;

  kA<<<dim3(64, 4), 128, 0, stream>>>(X, W1, b1, ha, hb, ru);
  // kB tiles + G1f(L0) riders in one node
  nKbG1f<<<dim3(320, 4), 256, 0, stream>>>(ha, hb, C, W1, W2, b2, Km, ru,
                                           X, Wg, as_, ad_, xw, ssT, sdT);
  kCcol<<<dim3(16, 4), 512, 0, stream>>>(Km, ru, rvpA);
  // Sinkhorn chain with GAT/kF rider blocks packed into the nodes
  nCrcG2t<<<dim3(528, 4), 512, 0, stream>>>(Km, rvpA, rvpB, ru,
                                            xw, ssT, sdT, partial);            // it0 + G2t(L0)
  nCrcRed<<<dim3(48, 4), 512, 0, stream>>>(Km, rvpB, rvpA, ru,
                                           partial, bg, x1);                   // it1 + Red(L0)
  nCrcG1f<<<dim3(80, 4), 512, 0, stream>>>(Km, rvpA, rvpB, ru,
                                           x1, Wg + 65536, as_ + 512, ad_ + 512,
                                           xw, ssT, sdT);                      // it2 + G1f(L1)
  nCrcG2t<<<dim3(528, 4), 512, 0, stream>>>(Km, rvpB, rvpA, ru,
                                            xw, ssT, sdT, partial);            // it3 + G2t(L1)
  nCrcRed<<<dim3(48, 4), 512, 0, stream>>>(Km, rvpA, rvpB, ru,
                                           partial, bg + 128, x2);             // it4 + Red(L1)
  nCrcFp<<<dim3(80, 4), 512, 0, stream>>>(Km, rvpB, rvpA, ru, x2, out, 0);     // it5 + F[0:64)
  nCrcFp<<<dim3(80, 4), 512, 0, stream>>>(Km, rvpA, rvpB, ru, x2, out, 64);    // it6 + F[64:128)
  nCrcFp<<<dim3(80, 4), 512, 0, stream>>>(Km, rvpB, rvpA, ru, x2, out, 128);   // it7 + F[128:192)
  nCrcFp<<<dim3(80, 4), 512, 0, stream>>>(Km, rvpA, rvpB, ru, x2, out, 192);   // it8 + F[192:256)
  kAdj<<<dim3(16, 4), 512, 0, stream>>>(Km, ru, rvpB, adj);
}

// Round 15
// 157.450 us; speedup vs baseline: 1.0641x; 1.0641x over previous
//
#include <hip/hip_runtime.h>
#include <math.h>

#define NB 4
#define NN 512

// ---------------- kA: ha = X@Wa + b1, hb = X@Wb ; zero ru ----------------
__global__ void kA(const float* __restrict__ X, const float* __restrict__ W1,
                   const float* __restrict__ b1, float* __restrict__ ha,
                   float* __restrict__ hb, float* __restrict__ ru) {
  int b = blockIdx.y, n0 = blockIdx.x * 8;
  __shared__ float xs[8][128];
  int t = threadIdx.x;  // 128 threads
  for (int q = t; q < 1024; q += 128) {
    int r = q >> 7, f = q & 127;
    xs[r][f] = X[(size_t)(b * NN + n0 + r) * 128 + f];
  }
  int flat = b * 64 + blockIdx.x;
  if (flat < 16) ru[flat * 128 + t] = 0.f;
  __syncthreads();
  float accA[8] = {0,0,0,0,0,0,0,0}, accB[8] = {0,0,0,0,0,0,0,0};
  for (int f = 0; f < 128; ++f) {
    float wa = W1[f * 128 + t];
    float wb = W1[(128 + f) * 128 + t];
#pragma unroll
    for (int r = 0; r < 8; ++r) {
      accA[r] = fmaf(xs[r][f], wa, accA[r]);
      accB[r] = fmaf(xs[r][f], wb, accB[r]);
    }
  }
  float b1v = b1[t];
#pragma unroll
  for (int r = 0; r < 8; ++r) {
    ha[(size_t)(b * NN + n0 + r) * 128 + t] = accA[r] + b1v;
    hb[(size_t)(b * NN + n0 + r) * 128 + t] = accB[r];
  }
}

// ===== device roles =====================================================

// kB as a device role (256 thr): K tile + row-sum atomics.
__device__ __forceinline__ void dKb(const float* __restrict__ ha,
                                    const float* __restrict__ hb,
                                    const float* __restrict__ coords,
                                    const float* __restrict__ W1,
                                    const float* __restrict__ W2,
                                    const float* __restrict__ b2,
                                    float* __restrict__ Km,
                                    float* __restrict__ ru,
                                    float* sm, int jc, int ic, int b) {
  float* As = sm;
  float* Bs = sm + 4224;
  float* wd = sm + 8448;
  float* w2 = sm + 8576;
  float* ci = sm + 8704;
  float* cj = sm + 8800;
  int i0 = ic * 32, j0 = jc * 32;
  int t = threadIdx.x;  // 256
  for (int q = t; q < 1024; q += 256) {
    int r = q >> 5, c = (q & 31) * 4;
    *(float4*)&As[r * 132 + c] = *(const float4*)&ha[(size_t)(b * NN + i0 + r) * 128 + c];
    *(float4*)&Bs[r * 132 + c] = *(const float4*)&hb[(size_t)(b * NN + j0 + r) * 128 + c];
  }
  if (t < 128) { wd[t] = W1[256 * 128 + t]; w2[t] = W2[t]; }
  if (t < 96) ci[t] = coords[(size_t)(b * NN + i0) * 3 + t];
  else if (t < 192) cj[t - 96] = coords[(size_t)(b * NN + j0) * 3 + (t - 96)];
  __syncthreads();
  int tx = t & 15, ty = t >> 4;
  int ia = 2 * ty, ib = ia + 1, ja = tx, jb = tx + 16;
  float d00, d01, d10, d11;
  {
    float ax = ci[ia * 3], ay = ci[ia * 3 + 1], az = ci[ia * 3 + 2];
    float bx = ci[ib * 3], by = ci[ib * 3 + 1], bz = ci[ib * 3 + 2];
    float cx0 = cj[ja * 3], cy0 = cj[ja * 3 + 1], cz0 = cj[ja * 3 + 2];
    float cx1 = cj[jb * 3], cy1 = cj[jb * 3 + 1], cz1 = cj[jb * 3 + 2];
    float dx, dy, dz;
    dx = ax - cx0; dy = ay - cy0; dz = az - cz0;
    d00 = sqrtf(fmaxf(dx * dx + dy * dy + dz * dz, 0.f));
    dx = ax - cx1; dy = ay - cy1; dz = az - cz1;
    d01 = sqrtf(fmaxf(dx * dx + dy * dy + dz * dz, 0.f));
    dx = bx - cx0; dy = by - cy0; dz = bz - cz0;
    d10 = sqrtf(fmaxf(dx * dx + dy * dy + dz * dz, 0.f));
    dx = bx - cx1; dy = by - cy1; dz = bz - cz1;
    d11 = sqrtf(fmaxf(dx * dx + dy * dy + dz * dz, 0.f));
  }
  float a00 = 0, a01 = 0, a10 = 0, a11 = 0;
  for (int k = 0; k < 128; k += 4) {
    float4 A0 = *(float4*)&As[ia * 132 + k];
    float4 A1 = *(float4*)&As[ib * 132 + k];
    float4 B0 = *(float4*)&Bs[ja * 132 + k];
    float4 B1 = *(float4*)&Bs[jb * 132 + k];
    float4 W = *(float4*)&wd[k];
    float4 V = *(float4*)&w2[k];
#pragma unroll
    for (int kk = 0; kk < 4; ++kk) {
      float av = ((float*)&A0)[kk], av1 = ((float*)&A1)[kk];
      float bv = ((float*)&B0)[kk], bv1 = ((float*)&B1)[kk];
      float wv = ((float*)&W)[kk], vv = ((float*)&V)[kk];
      float t00 = fmaxf(fmaf(d00, wv, av + bv), 0.f);
      float t01 = fmaxf(fmaf(d01, wv, av + bv1), 0.f);
      float t10 = fmaxf(fmaf(d10, wv, av1 + bv), 0.f);
      float t11 = fmaxf(fmaf(d11, wv, av1 + bv1), 0.f);
      a00 = fmaf(t00, vv, a00);
      a01 = fmaf(t01, vv, a01);
      a10 = fmaf(t10, vv, a10);
      a11 = fmaf(t11, vv, a11);
    }
  }
  float b2v = b2[0];
  float k00 = __expf(-5.0f * (a00 + b2v));
  float k01 = __expf(-5.0f * (a01 + b2v));
  float k10 = __expf(-5.0f * (a10 + b2v));
  float k11 = __expf(-5.0f * (a11 + b2v));
  size_t r0 = (size_t)(b * NN + i0 + ia) * NN + j0;
  size_t r1 = (size_t)(b * NN + i0 + ib) * NN + j0;
  Km[r0 + ja] = k00; Km[r0 + jb] = k01;
  Km[r1 + ja] = k10; Km[r1 + jb] = k11;
  float s0 = k00 + k01, s1 = k10 + k11;
#pragma unroll
  for (int off = 1; off < 16; off <<= 1) {
    s0 += __shfl_xor(s0, off);
    s1 += __shfl_xor(s1, off);
  }
  if (tx == 0) {
    atomicAdd(&ru[b * NN + i0 + ia], s0);
    atomicAdd(&ru[b * NN + i0 + ib], s1);
  }
}

// GAT GEMM + logit projections, 256 thr (proven round-5 kG1f body).
__device__ __forceinline__ void dG1f256(const float* __restrict__ x,
                                        const float* __restrict__ Wg,
                                        const float* __restrict__ asrc,
                                        const float* __restrict__ adst,
                                        float* __restrict__ xw,
                                        float* __restrict__ ssT,
                                        float* __restrict__ sdT,
                                        float* sm, int bx, int b) {
  int n0 = bx * 8;
  float* xs = sm;           // [8][128]
  float* red = sm + 1024;   // [4][8][4]
  int t = threadIdx.x;  // 256
  for (int q = t; q < 1024; q += 256)
    xs[q] = x[(size_t)(b * NN + n0 + (q >> 7)) * 128 + (q & 127)];
  __syncthreads();
  int c0 = t, c1 = t + 256;
  float acc0[8] = {0,0,0,0,0,0,0,0}, acc1[8] = {0,0,0,0,0,0,0,0};
  for (int f = 0; f < 128; ++f) {
    float w0 = Wg[f * 512 + c0], w1 = Wg[f * 512 + c1];
#pragma unroll
    for (int r = 0; r < 8; ++r) {
      float xv = xs[r * 128 + f];
      acc0[r] = fmaf(xv, w0, acc0[r]);
      acc1[r] = fmaf(xv, w1, acc1[r]);
    }
  }
#pragma unroll
  for (int r = 0; r < 8; ++r) {
    xw[(size_t)(b * NN + n0 + r) * 512 + c0] = acc0[r];
    xw[(size_t)(b * NN + n0 + r) * 512 + c1] = acc1[r];
  }
  float as0 = asrc[c0], ad0 = adst[c0];
  float as1 = asrc[c1], ad1 = adst[c1];
  int w = t >> 6, l = t & 63;
#pragma unroll
  for (int r = 0; r < 8; ++r) {
    float ps0 = acc0[r] * as0, pd0 = acc0[r] * ad0;
    float ps1 = acc1[r] * as1, pd1 = acc1[r] * ad1;
#pragma unroll
    for (int off = 1; off < 64; off <<= 1) {
      ps0 += __shfl_xor(ps0, off);
      pd0 += __shfl_xor(pd0, off);
      ps1 += __shfl_xor(ps1, off);
      pd1 += __shfl_xor(pd1, off);
    }
    if (l == 0) {
      red[w * 32 + r * 4 + 0] = ps0; red[w * 32 + r * 4 + 1] = pd0;
      red[w * 32 + r * 4 + 2] = ps1; red[w * 32 + r * 4 + 3] = pd1;
    }
  }
  __syncthreads();
  if (t < 64) {
    int r = t & 7, h = (t >> 3) & 3, sd = t >> 5;
    int wbase = (h & 1) ? 2 : 0;
    int which = (h < 2 ? 0 : 2) + sd;
    float s = red[wbase * 32 + r * 4 + which] + red[(wbase + 1) * 32 + r * 4 + which];
    float* dst = sd ? sdT : ssT;
    dst[(size_t)(b * 4 + h) * 512 + n0 + r] = s;
  }
}

// Sinkhorn first col-partials: rvp[ic] = partial col sums of K * (1/ru)
__device__ __forceinline__ void dCcol(const float* __restrict__ Km,
                                      const float* __restrict__ ru,
                                      float* __restrict__ rvp,
                                      float* sm, int ic, int b) {
  float* uinv = sm;  // 32
  int t = threadIdx.x;
  if (t < 32) uinv[t] = 1.0f / ru[b * NN + ic * 32 + t];
  __syncthreads();
  const float* Kp = Km + (size_t)(b * NN + ic * 32) * NN + t;
  float acc = 0.f;
#pragma unroll 8
  for (int ii = 0; ii < 32; ++ii) acc = fmaf(Kp[(size_t)ii * NN], uinv[ii], acc);
  rvp[ic * 2048 + b * NN + t] = acc;
}

// Sinkhorn iteration: row pass + new col partials
__device__ __forceinline__ void dCrc(const float* __restrict__ Km,
                                     const float* __restrict__ rvpOld,
                                     float* __restrict__ rvpNew,
                                     float* __restrict__ ru,
                                     float* sm, int ic, int b) {
  float* vinv = sm;        // 512
  float* uinv = sm + 512;  // 32
  int t = threadIdx.x;
  {
    float s = 0.f;
#pragma unroll
    for (int q = 0; q < 16; ++q) s += rvpOld[q * 2048 + b * NN + t];
    vinv[t] = 1.0f / s;
  }
  __syncthreads();
  int w = t >> 6, l = t & 63;
#pragma unroll
  for (int m = 0; m < 4; ++m) {
    int r = ic * 32 + w * 4 + m;
    const float* Kp = Km + (size_t)(b * NN + r) * NN;
    float acc = 0.f;
#pragma unroll
    for (int mm = 0; mm < 8; ++mm) acc = fmaf(Kp[l + 64 * mm], vinv[l + 64 * mm], acc);
#pragma unroll
    for (int off = 1; off < 64; off <<= 1) acc += __shfl_xor(acc, off);
    if (l == 0) { uinv[w * 4 + m] = 1.0f / acc; ru[b * NN + r] = acc; }
  }
  __syncthreads();
  {
    const float* Kp = Km + (size_t)(b * NN + ic * 32) * NN + t;
    float acc = 0.f;
#pragma unroll 8
    for (int ii = 0; ii < 32; ++ii) acc = fmaf(Kp[(size_t)ii * NN], uinv[ii], acc);
    rvpNew[ic * 2048 + b * NN + t] = acc;
  }
}

// GAT GEMM + logit projections, 512 thr (layer-1 rider)
__device__ __forceinline__ void dG1f(const float* __restrict__ x,
                                     const float* __restrict__ Wg,
                                     const float* __restrict__ asrc,
                                     const float* __restrict__ adst,
                                     float* __restrict__ xw,
                                     float* __restrict__ ssT,
                                     float* __restrict__ sdT,
                                     float* sm, int bx, int b) {
  int n0 = bx * 8;
  float* xs = sm;          // 1024: [8][128]
  float* red = sm + 1024;  // 128
  int t = threadIdx.x;  // 512
  for (int q = t; q < 1024; q += 512)
    xs[q] = x[(size_t)(b * NN + n0 + (q >> 7)) * 128 + (q & 127)];
  __syncthreads();
  int c = t;
  float acc[8] = {0,0,0,0,0,0,0,0};
  for (int f = 0; f < 128; ++f) {
    float w0 = Wg[f * 512 + c];
#pragma unroll
    for (int r = 0; r < 8; ++r) acc[r] = fmaf(xs[r * 128 + f], w0, acc[r]);
  }
#pragma unroll
  for (int r = 0; r < 8; ++r)
    xw[(size_t)(b * NN + n0 + r) * 512 + c] = acc[r];
  float asv = asrc[c], adv = adst[c];
  int w = t >> 6, l = t & 63;
#pragma unroll
  for (int r = 0; r < 8; ++r) {
    float ps = acc[r] * asv, pd = acc[r] * adv;
#pragma unroll
    for (int off = 1; off < 64; off <<= 1) {
      ps += __shfl_xor(ps, off);
      pd += __shfl_xor(pd, off);
    }
    if (l == 0) { red[w * 16 + r * 2] = ps; red[w * 16 + r * 2 + 1] = pd; }
  }
  __syncthreads();
  if (t < 64) {
    int h = t >> 4, rr = t & 7, sd = (t >> 3) & 1;
    float s = red[(2 * h) * 16 + rr * 2 + sd] + red[(2 * h + 1) * 16 + rr * 2 + sd];
    float* dst = sd ? sdT : ssT;
    dst[(size_t)(b * 4 + h) * 512 + n0 + rr] = s;
  }
}

// GAT softmax+PV for ONE head, 8-row i-tile, 512 thr (proven r11/r13 body).
#define PLT 520
__device__ __forceinline__ void dG2t(const float* __restrict__ xw,
                                     const float* __restrict__ ssT,
                                     const float* __restrict__ sdT,
                                     float* __restrict__ partial,
                                     float* sm, int bx, int b) {
  int h = bx & 3, i0 = (bx >> 2) * 8;
  int bh = b * 4 + h;
  float* pls = sm;             // [8][520]; sc4 reuses sm
  float* ssb = sm + 8192;      // 512
  float* sdl = sm + 8704;      // 8
  float* smaxsh = sm + 8712;   // 8
  float* mxl = sm + 8720;      // 8
  int t = threadIdx.x;  // 512
  {
    float v = ssT[(size_t)bh * 512 + t];
    ssb[t] = v;
#pragma unroll
    for (int off = 1; off < 64; off <<= 1) v = fmaxf(v, __shfl_xor(v, off));
    if ((t & 63) == 0) smaxsh[t >> 6] = v;
  }
  if (t < 8) sdl[t] = sdT[(size_t)bh * 512 + i0 + t];
  __syncthreads();
  if (t < 8) {
    float m = smaxsh[0];
#pragma unroll
    for (int q = 1; q < 8; ++q) m = fmaxf(m, smaxsh[q]);
    float mm = sdl[t] + m;
    mxl[t] = (mm >= 0.f) ? mm : 0.2f * mm;
  }
  __syncthreads();
  {
    int il = t >> 6, jq = t & 63;
    float mx = mxl[il], sdv = sdl[il];
    float pe[8];
    float den = 0.f;
#pragma unroll
    for (int jj = 0; jj < 8; ++jj) {
      int j = jj * 64 + jq;
      float e = sdv + ssb[j];
      e = (e >= 0.f) ? e : 0.2f * e;
      pe[jj] = __expf(e - mx);
      den += pe[jj];
    }
#pragma unroll
    for (int off = 1; off < 64; off <<= 1) den += __shfl_xor(den, off);
    float inv = 1.0f / (4.0f * den);
#pragma unroll
    for (int jj = 0; jj < 8; ++jj) pls[il * PLT + jj * 64 + jq] = pe[jj] * inv;
  }
  __syncthreads();
  int fq = t & 31, jh = t >> 5;
  const float* xp = xw + (size_t)(b * NN) * 512 + h * 128 + fq * 4;
  float4 acc[8];
#pragma unroll
  for (int r = 0; r < 8; ++r) acc[r] = make_float4(0.f, 0.f, 0.f, 0.f);
  int jbase = jh * 32;
#pragma unroll 4
  for (int jj = 0; jj < 32; ++jj) {
    int j = jbase + jj;
    float4 xv = *(const float4*)&xp[(size_t)j * 512];
#pragma unroll
    for (int r = 0; r < 8; ++r) {
      float p = pls[r * PLT + j];
      acc[r].x = fmaf(p, xv.x, acc[r].x);
      acc[r].y = fmaf(p, xv.y, acc[r].y);
      acc[r].z = fmaf(p, xv.z, acc[r].z);
      acc[r].w = fmaf(p, xv.w, acc[r].w);
    }
  }
  __syncthreads();
  int w = t >> 6;
#pragma unroll
  for (int r = 0; r < 8; ++r) {
    acc[r].x += __shfl_xor(acc[r].x, 32);
    acc[r].y += __shfl_xor(acc[r].y, 32);
    acc[r].z += __shfl_xor(acc[r].z, 32);
    acc[r].w += __shfl_xor(acc[r].w, 32);
  }
  float4* sc4 = (float4*)sm;
  if ((t & 63) < 32) {
#pragma unroll
    for (int r = 0; r < 8; ++r) sc4[w * 256 + r * 32 + fq] = acc[r];
  }
  __syncthreads();
  if (t < 256) {
    int r = t >> 5, ff = t & 31;
    float4 s = make_float4(0.f, 0.f, 0.f, 0.f);
#pragma unroll
    for (int q = 0; q < 8; ++q) {
      float4 u = sc4[q * 256 + r * 32 + ff];
      s.x += u.x; s.y += u.y; s.z += u.z; s.w += u.w;
    }
    *(float4*)&partial[((size_t)bh * NN + i0 + r) * 128 + ff * 4] = s;
  }
}

// head-sum reduce: xo[b,i,f] = sum_h partial[b,h,i,f] + bg[f]
__device__ __forceinline__ void dRed(const float* __restrict__ partial,
                                     const float* __restrict__ bg,
                                     float* __restrict__ xo, int bx, int b) {
  int idx = bx * 512 + threadIdx.x;  // 0..16383 per b: i*32 + f4
  int f4 = idx & 31, i = idx >> 5;
  const float* pp = partial + (((size_t)b * 4) * NN + i) * 128 + f4 * 4;
  float4 s = *(const float4*)pp;
  const float* p1 = pp + (size_t)NN * 128;
  const float* p2 = pp + (size_t)2 * NN * 128;
  const float* p3 = pp + (size_t)3 * NN * 128;
  float4 v1 = *(const float4*)p1, v2 = *(const float4*)p2, v3 = *(const float4*)p3;
  float4 bb = *(const float4*)&bg[f4 * 4];
  s.x += v1.x + v2.x + v3.x + bb.x;
  s.y += v1.y + v2.y + v3.y + bb.y;
  s.z += v1.z + v2.z + v3.z + bb.z;
  s.w += v1.w + v2.w + v3.w + bb.w;
  *(float4*)&xo[(size_t)(b * NN + i) * 128 + f4 * 4] = s;
}

// final_adj tile, 512 thr: 32x32, 2 outputs/thread
__device__ __forceinline__ void dF(const float* __restrict__ x,
                                   float* __restrict__ out,
                                   float* sm, int fid, int b) {
  int i0 = (fid >> 4) * 32, j0 = (fid & 15) * 32;
  float* As = sm;          // [32][132]
  float* Bs = sm + 4224;   // [32][132]
  int t = threadIdx.x;  // 512
  for (int q = t; q < 1024; q += 512) {
    int r = q >> 5, c = (q & 31) * 4;
    *(float4*)&As[r * 132 + c] = *(const float4*)&x[(size_t)(b * NN + i0 + r) * 128 + c];
    *(float4*)&Bs[r * 132 + c] = *(const float4*)&x[(size_t)(b * NN + j0 + r) * 128 + c];
  }
  __syncthreads();
  int tx = t & 31, ty = t >> 5;
  int ia = 2 * ty, ib = ia + 1;
  float a0 = 0.f, a1 = 0.f;
  for (int k = 0; k < 128; k += 4) {
    float4 A0 = *(float4*)&As[ia * 132 + k];
    float4 A1 = *(float4*)&As[ib * 132 + k];
    float4 B0 = *(float4*)&Bs[tx * 132 + k];
#pragma unroll
    for (int kk = 0; kk < 4; ++kk) {
      a0 = fmaf(((float*)&A0)[kk], ((float*)&B0)[kk], a0);
      a1 = fmaf(((float*)&A1)[kk], ((float*)&B0)[kk], a1);
    }
  }
  out[(size_t)(b * NN + i0 + ia) * NN + j0 + tx] = 1.0f / (1.0f + __expf(-a0));
  out[(size_t)(b * NN + i0 + ib) * NN + j0 + tx] = 1.0f / (1.0f + __expf(-a1));
}

// ================= combined node kernels ================================

// kB tiles (bx < 256) + G1f(L0) riders (bx in [256, 320)), 256 thr
__global__ __launch_bounds__(256) void nKbG1f(
    const float* ha, const float* hb, const float* C, const float* W1,
    const float* W2, const float* b2, float* Km, float* ru,
    const float* X, const float* Wg, const float* as_, const float* ad_,
    float* xw, float* ssT, float* sdT) {
  __shared__ alignas(16) float sm[8896];
  if (blockIdx.x < 256)
    dKb(ha, hb, C, W1, W2, b2, Km, ru, sm, blockIdx.x & 15, blockIdx.x >> 4,
        blockIdx.y);
  else
    dG1f256(X, Wg, as_, ad_, xw, ssT, sdT, sm, blockIdx.x - 256, blockIdx.y);
}

__global__ __launch_bounds__(512) void kCcol(
    const float* Km, const float* ru, float* rvp) {
  __shared__ float sm[32];
  dCcol(Km, ru, rvp, sm, blockIdx.x, blockIdx.y);
}

__global__ __launch_bounds__(512) void nCrcG2t(
    const float* Km, const float* rvpOld, float* rvpNew, float* ru,
    const float* xw, const float* ssT, const float* sdT, float* partial) {
  __shared__ alignas(16) float sm[8728];
  if (blockIdx.x < 16) dCrc(Km, rvpOld, rvpNew, ru, sm, blockIdx.x, blockIdx.y);
  else dG2t(xw, ssT, sdT, partial, sm, blockIdx.x - 16, blockIdx.y);
}

__global__ __launch_bounds__(512) void nCrcRed(
    const float* Km, const float* rvpOld, float* rvpNew, float* ru,
    const float* partial, const float* bg, float* xo) {
  __shared__ alignas(16) float sm[544];
  if (blockIdx.x < 16) dCrc(Km, rvpOld, rvpNew, ru, sm, blockIdx.x, blockIdx.y);
  else dRed(partial, bg, xo, blockIdx.x - 16, blockIdx.y);
}

__global__ __launch_bounds__(512) void nCrcG1f(
    const float* Km, const float* rvpOld, float* rvpNew, float* ru,
    const float* x, const float* Wg, const float* as_, const float* ad_,
    float* xw, float* ssT, float* sdT) {
  __shared__ alignas(16) float sm[1280];
  if (blockIdx.x < 16) dCrc(Km, rvpOld, rvpNew, ru, sm, blockIdx.x, blockIdx.y);
  else dG1f(x, Wg, as_, ad_, xw, ssT, sdT, sm, blockIdx.x - 16, blockIdx.y);
}

// crc + 64-tile slice of final_adj (kF spread across the trailing chain)
__global__ __launch_bounds__(512) void nCrcFp(
    const float* Km, const float* rvpOld, float* rvpNew, float* ru,
    const float* x, float* outF, int fbase) {
  __shared__ alignas(16) float sm[8448];
  if (blockIdx.x < 16) dCrc(Km, rvpOld, rvpNew, ru, sm, blockIdx.x, blockIdx.y);
  else dF(x, outF, sm, fbase + (blockIdx.x - 16), blockIdx.y);
}

// ------- kAdj: adj = (1/ru_i) * K * (1/rv_j) -----------------------------
__global__ __launch_bounds__(512) void kAdj(const float* __restrict__ Km,
                                            const float* __restrict__ ru,
                                            const float* __restrict__ rvp,
                                            float* __restrict__ out) {
  int rc = blockIdx.x, b = blockIdx.y;  // (16, 4)
  __shared__ float vinv[512];
  __shared__ float uinv[32];
  int t = threadIdx.x;  // 512
  {
    float s = 0.f;
#pragma unroll
    for (int ic = 0; ic < 16; ++ic) s += rvp[ic * 2048 + b * NN + t];
    vinv[t] = 1.0f / s;
  }
  if (t < 32) uinv[t] = 1.0f / ru[b * NN + rc * 32 + t];
  __syncthreads();
  float vj = vinv[t];
  const float* Kp = Km + (size_t)(b * NN + rc * 32) * NN + t;
  float* op = out + (size_t)(b * NN + rc * 32) * NN + t;
#pragma unroll 4
  for (int m = 0; m < 32; ++m) {
    op[(size_t)m * NN] = Kp[(size_t)m * NN] * uinv[m] * vj;
  }
}

extern "C" void kernel_launch(void* const* d_in, const int* in_sizes, int n_in,
                              void* d_out, int out_size, void* d_ws, size_t ws_size,
                              hipStream_t stream) {
  (void)in_sizes; (void)n_in; (void)out_size; (void)ws_size;
  const float* X   = (const float*)d_in[0];
  const float* C   = (const float*)d_in[1];
  const float* W1  = (const float*)d_in[2];
  const float* b1  = (const float*)d_in[3];
  const float* W2  = (const float*)d_in[4];
  const float* b2  = (const float*)d_in[5];
  const float* Wg  = (const float*)d_in[6];
  const float* as_ = (const float*)d_in[7];
  const float* ad_ = (const float*)d_in[8];
  const float* bg  = (const float*)d_in[9];
  float* out = (float*)d_out;
  float* ws = (float*)d_ws;

  float* ha    = ws;                 // 262144
  float* hb    = ws + 262144;        // 262144
  float* Km    = ws + 524288;        // 1048576
  float* ru    = ws + 1572864;       // 2048
  float* xw    = ws + 1591296;       // 1048576
  float* ssT   = ws + 2639872;       // 8192
  float* sdT   = ws + 2648064;       // 8192
  float* x1    = ws + 2656256;       // 262144
  float* x2    = ws + 2918400;       // 262144
  float* rvpA  = ws + 3180544;       // 32768
  float* rvpB  = ws + 3246080;       // 32768
  float* adj   = out + 1048576;
  // partial aliases out[0..1048576): final_adj region written only by the
  // nCrcFp nodes (it5..it8); partial is dead after each layer's Red node.
  float* partial = out;

  kA<<<dim3(64, 4), 128, 0, stream>>>(X, W1, b1, ha, hb, ru);
  // kB tiles + G1f(L0) riders in one node
  nKbG1f<<<dim3(320, 4), 256, 0, stream>>>(ha, hb, C, W1, W2, b2, Km, ru,
                                           X, Wg, as_, ad_, xw, ssT, sdT);
  kCcol<<<dim3(16, 4), 512, 0, stream>>>(Km, ru, rvpA);
  // Sinkhorn chain with GAT/kF rider blocks packed into the nodes
  nCrcG2t<<<dim3(272, 4), 512, 0, stream>>>(Km, rvpA, rvpB, ru,
                                            xw, ssT, sdT, partial);            // it0 + G2t(L0)
  nCrcRed<<<dim3(48, 4), 512, 0, stream>>>(Km, rvpB, rvpA, ru,
                                           partial, bg, x1);                   // it1 + Red(L0)
  nCrcG1f<<<dim3(80, 4), 512, 0, stream>>>(Km, rvpA, rvpB, ru,
                                           x1, Wg + 65536, as_ + 512, ad_ + 512,
                                           xw, ssT, sdT);                      // it2 + G1f(L1)
  nCrcG2t<<<dim3(272, 4), 512, 0, stream>>>(Km, rvpB, rvpA, ru,
                                            xw, ssT, sdT, partial);            // it3 + G2t(L1)
  nCrcRed<<<dim3(48, 4), 512, 0, stream>>>(Km, rvpA, rvpB, ru,
                                           partial, bg + 128, x2);             // it4 + Red(L1)
  nCrcFp<<<dim3(80, 4), 512, 0, stream>>>(Km, rvpB, rvpA, ru, x2, out, 0);     // it5 + F[0:64)
  nCrcFp<<<dim3(80, 4), 512, 0, stream>>>(Km, rvpA, rvpB, ru, x2, out, 64);    // it6 + F[64:128)
  nCrcFp<<<dim3(80, 4), 512, 0, stream>>>(Km, rvpB, rvpA, ru, x2, out, 128);   // it7 + F[128:192)
  nCrcFp<<<dim3(80, 4), 512, 0, stream>>>(Km, rvpA, rvpB, ru, x2, out, 192);   // it8 + F[192:256)
  kAdj<<<dim3(16, 4), 512, 0, stream>>>(Km, ru, rvpB, adj);
}